// Round 9
// baseline (124.924 us; speedup 1.0000x reference)
//
#include <hip/hip_runtime.h>
#include <cstdint>
#include <cstddef>

// Problem constants
#define BB 4
#define NN 20000
#define KK 16
#define MM 9
#define CC 64
#define OO 64
#define BN (BB*NN)       // 80000 nodes
#define MC (MM*CC)       // 576 flattened reduction dim
#define UVP 16           // uxc row pitch fp32: 9 used + 7 pad(-1e30) = 64B line
#define NKS (MC/32)      // 18 K-steps in Phase C
#define NCH 625          // 32-node chunks per batch
#define LOG2E 1.44269504089f

typedef _Float16 f16x8 __attribute__((ext_vector_type(8)));
typedef _Float16 f16x4 __attribute__((ext_vector_type(4)));
typedef __fp16   fp16v2 __attribute__((ext_vector_type(2)));   // pkrtz return type
typedef float    f32x4 __attribute__((ext_vector_type(4)));
typedef unsigned short u16;
typedef unsigned int   u32;

union Hcv { _Float16 h; u16 u; };
__device__ __forceinline__ u16 f2h(float f) { Hcv t; t.h = (_Float16)f; return t.u; }
__device__ __forceinline__ float h2f(u16 h) { Hcv t; t.u = h; return (float)t.h; }

__device__ __forceinline__ f16x4 tr_read(u32 addr) {
    f16x4 r;
    asm volatile("ds_read_b64_tr_b16 %0, %1 offset:0" : "=v"(r) : "v"(addr) : "memory");
    return r;
}

// ---------------------------------------------------------------------------
// Pre-pass: blocks <1250: x -> xh f16 cast + u-side GEMM -> uxc = (u.x+c)*log2e,
// rows padded with -1e30 (m=9..15) so fused needs NO softmax masking and can
// use bare v_exp_f32 (exp2). Blocks 1250..1285: W -> wfb2 fragment swizzle.
// 1286: v -> A-frag table vfa, scaled by log2e.
// ---------------------------------------------------------------------------
__global__ __launch_bounds__(256) void pre_kernel(
    const float* __restrict__ x, const float* __restrict__ W,
    const float* __restrict__ u, const float* __restrict__ v,
    const float* __restrict__ c,
    float* __restrict__ uxc, u16* __restrict__ xh,
    u16* __restrict__ wfb2, u16* __restrict__ vfa)
{
    const int bid = blockIdx.x;
    if (bid == 1286) {                        // v A-frag table: 1024 u16
        int i0 = threadIdx.x * 4;
        if (i0 < 1024) {
            u16 w4[4];
            #pragma unroll
            for (int tt = 0; tt < 4; ++tt) {
                int i = i0 + tt;
                int l = i >> 4, s = (i >> 3) & 1, j = i & 7;
                int m = l & 15, hh = l >> 4;
                float val = (m < 9) ? v[m * 64 + s * 32 + hh * 8 + j] * LOG2E : 0.f;
                w4[tt] = f2h(val);
            }
            *(ushort4*)(vfa + i0) = *(ushort4*)(w4);
        }
        return;
    }
    if (bid >= 1250) {                        // W swizzle: 36*1024 = 36864 elems
        int base = (bid - 1250) * 1024 + threadIdx.x * 4;
        ushort4 wv;
        u16* wp = (u16*)&wv;
        #pragma unroll
        for (int t = 0; t < 4; ++t) {
            int i = base + t;
            int j = i & 7, o = (i >> 3) & 63, l2 = (i >> 9) & 3, ks = i >> 11;
            int kf = ks * 32 + l2 * 8 + j;
            int m = kf >> 6, cc2 = kf & 63;
            wp[t] = f2h(W[m * 4096 + o * 64 + cc2]);
        }
        *(ushort4*)(wfb2 + base) = wv;
        return;
    }
    const int wave = threadIdx.x >> 6, lane = threadIdx.x & 63;
    const int lr = lane & 15, lhi = lane >> 4;
    const int t0n = bid * 64 + wave * 16;

    const float* xr = x + (size_t)(t0n + lr) * 64 + lhi * 8;
    float xf[16];
    *(float4*)(xf + 0)  = *(const float4*)(xr + 0);
    *(float4*)(xf + 4)  = *(const float4*)(xr + 4);
    *(float4*)(xf + 8)  = *(const float4*)(xr + 32);
    *(float4*)(xf + 12) = *(const float4*)(xr + 36);
    union { u16 us[8]; f16x8 v; ushort4 s4[2]; } H0, L0, H1, L1;
    #pragma unroll
    for (int i = 0; i < 8; ++i) {
        u16 h = f2h(xf[i]);      H0.us[i] = h;  L0.us[i] = f2h(xf[i] - h2f(h));
        u16 h2 = f2h(xf[8 + i]); H1.us[i] = h2; L1.us[i] = f2h(xf[8 + i] - h2f(h2));
    }
    u16* xw = xh + (size_t)(t0n + lr) * 64 + lhi * 8;
    *(ushort4*)(xw)          = H0.s4[0];
    *(ushort4*)(xw + 4)      = H0.s4[1];
    *(ushort4*)(xw + 32)     = H1.s4[0];
    *(ushort4*)(xw + 32 + 4) = H1.s4[1];

    // u-side GEMM only: D col=m(lr), row=node(lhi*4+reg)
    f32x4 acc = {0.f,0.f,0.f,0.f};
    const float* gp = u + lr * 64;
    bool nz = lr < 9;
    #pragma unroll
    for (int s = 0; s < 2; ++s) {
        float gf[8];
        *(float4*)(gf + 0) = nz ? *(const float4*)(gp + s * 32 + lhi * 8)
                                : make_float4(0.f,0.f,0.f,0.f);
        *(float4*)(gf + 4) = nz ? *(const float4*)(gp + s * 32 + lhi * 8 + 4)
                                : make_float4(0.f,0.f,0.f,0.f);
        union { u16 us[8]; f16x8 v; } GH, GL;
        #pragma unroll
        for (int i = 0; i < 8; ++i) {
            u16 h = f2h(gf[i]); GH.us[i] = h; GL.us[i] = f2h(gf[i] - h2f(h));
        }
        f16x8 as  = s ? H1.v : H0.v;
        f16x8 asl = s ? L1.v : L0.v;
        acc = __builtin_amdgcn_mfma_f32_16x16x32_f16(as,  GH.v, acc, 0, 0, 0);
        acc = __builtin_amdgcn_mfma_f32_16x16x32_f16(as,  GL.v, acc, 0, 0, 0);
        acc = __builtin_amdgcn_mfma_f32_16x16x32_f16(asl, GH.v, acc, 0, 0, 0);
    }
    float cv = (lr < 9) ? c[lr] : 0.f;
    #pragma unroll
    for (int reg = 0; reg < 4; ++reg) {
        int node = t0n + lhi * 4 + reg;
        // m<9: (u.x + c)*log2e; m=9..15: -1e30 so exp2() self-masks in fused
        uxc[(size_t)node * UVP + lr] =
            (lr < 9) ? ((acc[reg] + cv) * LOG2E) : -1e30f;
    }
}

// ---------------------------------------------------------------------------
// Fused (R8 structure) + residual shavings:
//   - exp2 folding: uxc/vfa pre-scaled by log2e -> bare v_exp_f32 in softmax
//   - Phase C W-frag prefetch (ks=0..3) before the barrier: the barrier's
//     vmcnt drain completes them under Bcomp's tail
//   - s_setprio(1) around the Bcomp MFMA cluster (independent phase-staggered
//     blocks -> attn-like regime, m191)
// LDS 53248 B -> 3 blocks/CU.  Layouts (m89/m101/m121-128): 16x16x32:
// A row=lane&15, k=(lane>>4)*8+j; B col=lane&15; D col=lane&15,
// row=(lane>>4)*4+reg. tr_read (m156/m162): frag[l][j]=lds[(l&15)+j*16+(l>>4)*64].
// ---------------------------------------------------------------------------
__global__ __launch_bounds__(256, 3) void fused_kernel(
    const u16* __restrict__ xh, const int* __restrict__ adj,
    const float* __restrict__ uxc, const u16* __restrict__ wfb2,
    const u16* __restrict__ vfa, const float* __restrict__ bias,
    float* __restrict__ out)
{
    __shared__ __align__(16) u16 qlds[8192];        // 16 KB [wave][t][g][16k][16m]
    __shared__ __align__(16) u16 slds[72 * 32 * 8]; // 36864 B
    const int bid = blockIdx.x;
    const int grp = bid & 7;                       // XCD id (round-robin)
    const int b = grp >> 1;                        // batch owned by XCD pair
    const int chunk = (bid >> 3) * 2 + (grp & 1);
    if (chunk >= NCH) return;                      // 4 pad blocks exit
    const int tid = threadIdx.x, wave = tid >> 6, lane = tid & 63;
    const int lr = lane & 15, lhi = lane >> 4;
    const int node0 = b * NN + chunk * 32;
    const int rowbase = b * NN;
    const u16* xhb = xh + ((size_t)rowbase << 6);

    int jjA[2];
    jjA[0] = adj[(size_t)node0 * KK + tid];        // tile0
    jjA[1] = adj[(size_t)node0 * KK + 256 + tid];  // tile1

    // ---- uxc broadcasts ((u.x+c)*log2e | -1e30 pad), one 64B line/row ----
    float4 uc[2][4];
    #pragma unroll
    for (int t = 0; t < 2; ++t)
        #pragma unroll
        for (int g2 = 0; g2 < 4; ++g2)
            uc[t][g2] = *(const float4*)(uxc +
                          (size_t)(node0 + t * 16 + wave * 4 + g2) * UVP + lhi * 4);

    // ---- constant v A-frags (pre-scaled by log2e) ----
    const u16* vp = vfa + lane * 16;
    const f16x8 vAlo = *(const f16x8*)(vp);
    const f16x8 vAhi = *(const f16x8*)(vp + 8);

    // ---- xh gathers for BOTH tiles (stay in flight under Phase A) ----
    f16x8 gLo[2][4], gHi[2][4];
    #pragma unroll
    for (int t = 0; t < 2; ++t)
        #pragma unroll
        for (int g2 = 0; g2 < 4; ++g2) {
            int e = __builtin_amdgcn_ds_bpermute((g2 * 16 + lr) * 4, jjA[t]);
            int erow = ((e > 0) ? e : 1) - 1;      // pad -> row 0 (q=0 kills)
            const u16* rp = xhb + ((size_t)erow << 6) + lhi * 8;
            gLo[t][g2] = *(const f16x8*)(rp);
            gHi[t][g2] = *(const f16x8*)(rp + 32);
        }

    // identity-selector B-frags for the transpose-MFMA
    f16x8 idf[2];
    #pragma unroll
    for (int s = 0; s < 2; ++s) {
        union { u16 us[8]; f16x8 v; } t;
        #pragma unroll
        for (int j = 0; j < 8; ++j)
            t.us[j] = (lhi * 8 + j == s * 16 + lr) ? (u16)0x3C00 : (u16)0;
        idf[s] = t.v;
    }

    unsigned long long bal0 = __ballot(jjA[0] != 0);
    unsigned long long bal1 = __ballot(jjA[1] != 0);

    // ---- Phase A (both tiles): logits MFMA + lean softmax + q -> qlds ----
    u16* qwb = qlds + wave * 2048 + lr * 16 + lhi * 4;
    #pragma unroll
    for (int t = 0; t < 2; ++t) {
        unsigned long long bal = t ? bal1 : bal0;
        #pragma unroll
        for (int g2 = 0; g2 < 4; ++g2) {
            f32x4 acc = {0.f, 0.f, 0.f, 0.f};
            acc = __builtin_amdgcn_mfma_f32_16x16x32_f16(vAlo, gLo[t][g2], acc, 0, 0, 0);
            acc = __builtin_amdgcn_mfma_f32_16x16x32_f16(vAhi, gHi[t][g2], acc, 0, 0, 0);
            u32 field = (u32)(bal >> (g2 * 16)) & 0xffffu;
            int  deg  = __popc(field);
            int  kbit = (field >> lr) & 1;
            const float* ucp = (const float*)&uc[t][g2];
            // operands pre-scaled by log2e -> bare v_exp_f32; m>=9 self-masks
            float p0 = __builtin_exp2f(acc[0] + ucp[0]);
            float p1 = __builtin_exp2f(acc[1] + ucp[1]);
            float p2 = __builtin_exp2f(acc[2] + ucp[2]);
            float p3 = __builtin_exp2f(acc[3] + ucp[3]);
            float S = (p0 + p1) + (p2 + p3);
            S += __shfl_xor(S, 16);
            S += __shfl_xor(S, 32);
            float qsc = kbit ? __fdividef(1.0f, (float)deg * S) : 0.0f;
            union { fp16v2 h2[2]; uint2 u2; } qp;
            qp.h2[0] = __builtin_amdgcn_cvt_pkrtz(p0 * qsc, p1 * qsc);
            qp.h2[1] = __builtin_amdgcn_cvt_pkrtz(p2 * qsc, p3 * qsc);
            // q[k=lr][m=lhi*4..+3] into node (t,g2)'s [16k][16m] subtile
            *(uint2*)(qwb + t * 1024 + g2 * 256) = qp.u2;
        }
    }
    asm volatile("s_waitcnt lgkmcnt(0)" ::: "memory");  // q writes retired
    // ---- qf via hardware-transpose reads (one batch, 8 frags) ----
    const u32 qtr = (u32)(size_t)qlds + wave * 4096 + lane * 8;
    f16x4 qf[2][4];
    #pragma unroll
    for (int t = 0; t < 2; ++t)
        #pragma unroll
        for (int g2 = 0; g2 < 4; ++g2)
            qf[t][g2] = tr_read(qtr + t * 2048 + g2 * 512);
    asm volatile("s_waitcnt lgkmcnt(0)" ::: "memory");
    __builtin_amdgcn_sched_barrier(0);                  // rule #18

    // ---- Bcomp (transpose+contract pair, pkrtz pack) -> slds ----
    const int o0 = wave * 16;
    __builtin_amdgcn_s_setprio(1);
    #pragma unroll
    for (int t = 0; t < 2; ++t)
        #pragma unroll
        for (int g2 = 0; g2 < 4; ++g2) {
            const int rnode = t * 16 + wave * 4 + g2;
            #pragma unroll
            for (int cc = 0; cc < 4; ++cc) {
                f32x4 xt = {0.f,0.f,0.f,0.f};
                xt = __builtin_amdgcn_mfma_f32_16x16x32_f16(
                         (cc < 2) ? gLo[t][g2] : gHi[t][g2], idf[cc & 1], xt, 0, 0, 0);
                union { fp16v2 h2[2]; f16x4 h4; } at;
                at.h2[0] = __builtin_amdgcn_cvt_pkrtz(xt[0], xt[1]);
                at.h2[1] = __builtin_amdgcn_cvt_pkrtz(xt[2], xt[3]);
                f32x4 d2 = {0.f,0.f,0.f,0.f};
                d2 = __builtin_amdgcn_mfma_f32_16x16x16f16(at.h4, qf[t][g2], d2, 0, 0, 0);
                union { fp16v2 h2[2]; uint2 u2; } sp;
                sp.h2[0] = __builtin_amdgcn_cvt_pkrtz(d2[0], d2[1]);
                sp.h2[1] = __builtin_amdgcn_cvt_pkrtz(d2[2], d2[3]);
                if (lr < 9) {
                    // kf = lr*64 + cc*16 + lhi*4 ; q = kf>>3 ; m = kf>>6 = lr
                    int q_ = lr * 8 + cc * 2 + (lhi >> 1);
                    int idx = (((q_ * 32 + rnode) << 3) ^ ((lr & 7) << 3)) + (lhi & 1) * 4;
                    *(uint2*)(slds + idx) = sp.u2;
                }
            }
        }
    __builtin_amdgcn_s_setprio(0);

    // ---- W-frag prefetch for ks=0..3 (completed by the barrier's drain) ----
    f16x8 bpre[4];
    #pragma unroll
    for (int ks = 0; ks < 4; ++ks)
        bpre[ks] = *(const f16x8*)(wfb2 + (size_t)((ks * 4 + lhi) * 64 + o0 + lr) * 8);
    __syncthreads();

    // ---- Phase C (merged, each bf load feeds both tiles) ----
    const float bv = bias[o0 + lr];
    f32x4 a0 = {0.f,0.f,0.f,0.f}, a1 = {0.f,0.f,0.f,0.f};
    #pragma unroll
    for (int ks = 0; ks < NKS; ++ks) {
        int q_ = ks * 4 + lhi;                     // m = q_>>3 (wave-uniform per ks)
        int sw = ((q_ >> 3) & 7) << 3;
        f16x8 af0 = *(const f16x8*)(slds + ((((q_ * 32) + lr) << 3) ^ sw));
        f16x8 af1 = *(const f16x8*)(slds + ((((q_ * 32) + 16 + lr) << 3) ^ sw));
        f16x8 bf  = (ks < 4) ? bpre[ks]
                  : *(const f16x8*)(wfb2 + (size_t)(q_ * 64 + o0 + lr) * 8);
        a0 = __builtin_amdgcn_mfma_f32_16x16x32_f16(af0, bf, a0, 0, 0, 0);
        a1 = __builtin_amdgcn_mfma_f32_16x16x32_f16(af1, bf, a1, 0, 0, 0);
    }
    #pragma unroll
    for (int r = 0; r < 4; ++r) {
        out[(size_t)(node0 + lhi * 4 + r) * OO + o0 + lr]      = a0[r] + bv;
        out[(size_t)(node0 + 16 + lhi * 4 + r) * OO + o0 + lr] = a1[r] + bv;
    }
}

// ---------------------------------------------------------------------------
extern "C" void kernel_launch(void* const* d_in, const int* in_sizes, int n_in,
                              void* d_out, int out_size, void* d_ws, size_t ws_size,
                              hipStream_t stream)
{
    const float* x   = (const float*)d_in[0];
    const int*   adj = (const int*)  d_in[1];
    const float* W   = (const float*)d_in[2];
    const float* b   = (const float*)d_in[3];
    const float* u   = (const float*)d_in[4];
    const float* v   = (const float*)d_in[5];
    const float* c   = (const float*)d_in[6];
    float* out = (float*)d_out;

    // workspace: uxc f32 [BN*16] | xh f16 [BN*64] | wfb2 [36864] | vfa [1024]
    float* uxc  = (float*)d_ws;
    u16*   xh   = (u16*)(uxc + (size_t)BN * UVP);
    u16*   wfb2 = xh + (size_t)BN * CC;
    u16*   vfa  = wfb2 + 36864;

    pre_kernel<<<1287, 256, 0, stream>>>(x, W, u, v, c, uxc, xh, wfb2, vfa);
    fused_kernel<<<2504, 256, 0, stream>>>(xh, adj, uxc, wfb2, vfa, b, out);
}

// Round 10
// 123.701 us; speedup vs baseline: 1.0099x; 1.0099x over previous
//
#include <hip/hip_runtime.h>
#include <cstdint>
#include <cstddef>

// Problem constants
#define BB 4
#define NN 20000
#define KK 16
#define MM 9
#define CC 64
#define OO 64
#define BN (BB*NN)       // 80000 nodes
#define MC (MM*CC)       // 576 flattened reduction dim
#define UVP 16           // uxc row pitch fp32: 9 used + 7 pad(-1e30) = 64B line
#define NKS (MC/32)      // 18 K-steps in Phase C
#define NCH 625          // 32-node chunks per batch

typedef _Float16 f16x8 __attribute__((ext_vector_type(8)));
typedef _Float16 f16x4 __attribute__((ext_vector_type(4)));
typedef __fp16   fp16v2 __attribute__((ext_vector_type(2)));   // pkrtz return type
typedef float    f32x4 __attribute__((ext_vector_type(4)));
typedef unsigned short u16;
typedef unsigned int   u32;

union Hcv { _Float16 h; u16 u; };
__device__ __forceinline__ u16 f2h(float f) { Hcv t; t.h = (_Float16)f; return t.u; }
__device__ __forceinline__ float h2f(u16 h) { Hcv t; t.u = h; return (float)t.h; }

__device__ __forceinline__ f16x4 tr_read(u32 addr) {
    f16x4 r;
    asm volatile("ds_read_b64_tr_b16 %0, %1 offset:0" : "=v"(r) : "v"(addr) : "memory");
    return r;
}

// ---------------------------------------------------------------------------
// Pre-pass: blocks <1250: x -> xh f16 cast + u-side GEMM -> uxc = u.x + c,
// rows padded with -1e30 (m=9..15) so fused needs NO softmax masking.
// Blocks 1250..1285: W -> wfb2 fragment swizzle. 1286: v -> A-frag table vfa.
// ---------------------------------------------------------------------------
__global__ __launch_bounds__(256) void pre_kernel(
    const float* __restrict__ x, const float* __restrict__ W,
    const float* __restrict__ u, const float* __restrict__ v,
    const float* __restrict__ c,
    float* __restrict__ uxc, u16* __restrict__ xh,
    u16* __restrict__ wfb2, u16* __restrict__ vfa)
{
    const int bid = blockIdx.x;
    if (bid == 1286) {                        // v A-frag table: 1024 u16
        int i0 = threadIdx.x * 4;
        if (i0 < 1024) {
            u16 w4[4];
            #pragma unroll
            for (int tt = 0; tt < 4; ++tt) {
                int i = i0 + tt;
                int l = i >> 4, s = (i >> 3) & 1, j = i & 7;
                int m = l & 15, hh = l >> 4;
                float val = (m < 9) ? v[m * 64 + s * 32 + hh * 8 + j] : 0.f;
                w4[tt] = f2h(val);
            }
            *(ushort4*)(vfa + i0) = *(ushort4*)(w4);
        }
        return;
    }
    if (bid >= 1250) {                        // W swizzle: 36*1024 = 36864 elems
        int base = (bid - 1250) * 1024 + threadIdx.x * 4;
        ushort4 wv;
        u16* wp = (u16*)&wv;
        #pragma unroll
        for (int t = 0; t < 4; ++t) {
            int i = base + t;
            int j = i & 7, o = (i >> 3) & 63, l2 = (i >> 9) & 3, ks = i >> 11;
            int kf = ks * 32 + l2 * 8 + j;
            int m = kf >> 6, cc2 = kf & 63;
            wp[t] = f2h(W[m * 4096 + o * 64 + cc2]);
        }
        *(ushort4*)(wfb2 + base) = wv;
        return;
    }
    const int wave = threadIdx.x >> 6, lane = threadIdx.x & 63;
    const int lr = lane & 15, lhi = lane >> 4;
    const int t0n = bid * 64 + wave * 16;

    const float* xr = x + (size_t)(t0n + lr) * 64 + lhi * 8;
    float xf[16];
    *(float4*)(xf + 0)  = *(const float4*)(xr + 0);
    *(float4*)(xf + 4)  = *(const float4*)(xr + 4);
    *(float4*)(xf + 8)  = *(const float4*)(xr + 32);
    *(float4*)(xf + 12) = *(const float4*)(xr + 36);
    union { u16 us[8]; f16x8 v; ushort4 s4[2]; } H0, L0, H1, L1;
    #pragma unroll
    for (int i = 0; i < 8; ++i) {
        u16 h = f2h(xf[i]);      H0.us[i] = h;  L0.us[i] = f2h(xf[i] - h2f(h));
        u16 h2 = f2h(xf[8 + i]); H1.us[i] = h2; L1.us[i] = f2h(xf[8 + i] - h2f(h2));
    }
    u16* xw = xh + (size_t)(t0n + lr) * 64 + lhi * 8;
    *(ushort4*)(xw)          = H0.s4[0];
    *(ushort4*)(xw + 4)      = H0.s4[1];
    *(ushort4*)(xw + 32)     = H1.s4[0];
    *(ushort4*)(xw + 32 + 4) = H1.s4[1];

    // u-side GEMM only: D col=m(lr), row=node(lhi*4+reg)
    f32x4 acc = {0.f,0.f,0.f,0.f};
    const float* gp = u + lr * 64;
    bool nz = lr < 9;
    #pragma unroll
    for (int s = 0; s < 2; ++s) {
        float gf[8];
        *(float4*)(gf + 0) = nz ? *(const float4*)(gp + s * 32 + lhi * 8)
                                : make_float4(0.f,0.f,0.f,0.f);
        *(float4*)(gf + 4) = nz ? *(const float4*)(gp + s * 32 + lhi * 8 + 4)
                                : make_float4(0.f,0.f,0.f,0.f);
        union { u16 us[8]; f16x8 v; } GH, GL;
        #pragma unroll
        for (int i = 0; i < 8; ++i) {
            u16 h = f2h(gf[i]); GH.us[i] = h; GL.us[i] = f2h(gf[i] - h2f(h));
        }
        f16x8 as  = s ? H1.v : H0.v;
        f16x8 asl = s ? L1.v : L0.v;
        acc = __builtin_amdgcn_mfma_f32_16x16x32_f16(as,  GH.v, acc, 0, 0, 0);
        acc = __builtin_amdgcn_mfma_f32_16x16x32_f16(as,  GL.v, acc, 0, 0, 0);
        acc = __builtin_amdgcn_mfma_f32_16x16x32_f16(asl, GH.v, acc, 0, 0, 0);
    }
    float cv = (lr < 9) ? c[lr] : 0.f;
    #pragma unroll
    for (int reg = 0; reg < 4; ++reg) {
        int node = t0n + lhi * 4 + reg;
        // m<9: logit u-part; m=9..15: -1e30 so exp() self-masks in fused
        uxc[(size_t)node * UVP + lr] = (lr < 9) ? (acc[reg] + cv) : -1e30f;
    }
}

// ---------------------------------------------------------------------------
// Fused (best-measured configuration, R8):
//   - v-side logits via 2 MFMAs per node on the gathered rows (no vx stream)
//   - lean softmax: no max-sub (|logits|<=~10, expf-safe), -1e30 self-masking,
//     single divide
//   - one lgkmcnt wall; tr_read qf; Bcomp transpose+contract; merged Phase C
// LDS 53248 B -> 3 blocks/CU.  Layouts (m89/m101/m121-128): 16x16x32:
// A row=lane&15, k=(lane>>4)*8+j; B col=lane&15; D col=lane&15,
// row=(lane>>4)*4+reg. tr_read (m156/m162): frag[l][j]=lds[(l&15)+j*16+(l>>4)*64].
// ---------------------------------------------------------------------------
__global__ __launch_bounds__(256, 3) void fused_kernel(
    const u16* __restrict__ xh, const int* __restrict__ adj,
    const float* __restrict__ uxc, const u16* __restrict__ wfb2,
    const u16* __restrict__ vfa, const float* __restrict__ bias,
    float* __restrict__ out)
{
    __shared__ __align__(16) u16 qlds[8192];        // 16 KB [wave][t][g][16k][16m]
    __shared__ __align__(16) u16 slds[72 * 32 * 8]; // 36864 B
    const int bid = blockIdx.x;
    const int grp = bid & 7;                       // XCD id (round-robin)
    const int b = grp >> 1;                        // batch owned by XCD pair
    const int chunk = (bid >> 3) * 2 + (grp & 1);
    if (chunk >= NCH) return;                      // 4 pad blocks exit
    const int tid = threadIdx.x, wave = tid >> 6, lane = tid & 63;
    const int lr = lane & 15, lhi = lane >> 4;
    const int node0 = b * NN + chunk * 32;
    const int rowbase = b * NN;
    const u16* xhb = xh + ((size_t)rowbase << 6);

    int jjA[2];
    jjA[0] = adj[(size_t)node0 * KK + tid];        // tile0
    jjA[1] = adj[(size_t)node0 * KK + 256 + tid];  // tile1

    // ---- uxc broadcasts (u.x + c | -1e30 pad), one aligned 64B line/row ----
    float4 uc[2][4];
    #pragma unroll
    for (int t = 0; t < 2; ++t)
        #pragma unroll
        for (int g2 = 0; g2 < 4; ++g2)
            uc[t][g2] = *(const float4*)(uxc +
                          (size_t)(node0 + t * 16 + wave * 4 + g2) * UVP + lhi * 4);

    // ---- constant v A-frags ----
    const u16* vp = vfa + lane * 16;
    const f16x8 vAlo = *(const f16x8*)(vp);
    const f16x8 vAhi = *(const f16x8*)(vp + 8);

    // ---- xh gathers for BOTH tiles (stay in flight under Phase A) ----
    f16x8 gLo[2][4], gHi[2][4];
    #pragma unroll
    for (int t = 0; t < 2; ++t)
        #pragma unroll
        for (int g2 = 0; g2 < 4; ++g2) {
            int e = __builtin_amdgcn_ds_bpermute((g2 * 16 + lr) * 4, jjA[t]);
            int erow = ((e > 0) ? e : 1) - 1;      // pad -> row 0 (q=0 kills)
            const u16* rp = xhb + ((size_t)erow << 6) + lhi * 8;
            gLo[t][g2] = *(const f16x8*)(rp);
            gHi[t][g2] = *(const f16x8*)(rp + 32);
        }

    // identity-selector B-frags for the transpose-MFMA
    f16x8 idf[2];
    #pragma unroll
    for (int s = 0; s < 2; ++s) {
        union { u16 us[8]; f16x8 v; } t;
        #pragma unroll
        for (int j = 0; j < 8; ++j)
            t.us[j] = (lhi * 8 + j == s * 16 + lr) ? (u16)0x3C00 : (u16)0;
        idf[s] = t.v;
    }

    unsigned long long bal0 = __ballot(jjA[0] != 0);
    unsigned long long bal1 = __ballot(jjA[1] != 0);

    // ---- Phase A (both tiles): logits MFMA + lean softmax + q -> qlds ----
    u16* qwb = qlds + wave * 2048 + lr * 16 + lhi * 4;
    #pragma unroll
    for (int t = 0; t < 2; ++t) {
        unsigned long long bal = t ? bal1 : bal0;
        #pragma unroll
        for (int g2 = 0; g2 < 4; ++g2) {
            f32x4 acc = {0.f, 0.f, 0.f, 0.f};
            acc = __builtin_amdgcn_mfma_f32_16x16x32_f16(vAlo, gLo[t][g2], acc, 0, 0, 0);
            acc = __builtin_amdgcn_mfma_f32_16x16x32_f16(vAhi, gHi[t][g2], acc, 0, 0, 0);
            u32 field = (u32)(bal >> (g2 * 16)) & 0xffffu;
            int  deg  = __popc(field);
            int  kbit = (field >> lr) & 1;
            const float* ucp = (const float*)&uc[t][g2];
            // no max-sub; m>=9 self-masks via the -1e30 pad -> exp = 0
            float p0 = __expf(acc[0] + ucp[0]);
            float p1 = __expf(acc[1] + ucp[1]);
            float p2 = __expf(acc[2] + ucp[2]);
            float p3 = __expf(acc[3] + ucp[3]);
            float S = (p0 + p1) + (p2 + p3);
            S += __shfl_xor(S, 16);
            S += __shfl_xor(S, 32);
            float qsc = kbit ? __fdividef(1.0f, (float)deg * S) : 0.0f;
            union { fp16v2 h2[2]; uint2 u2; } qp;
            qp.h2[0] = __builtin_amdgcn_cvt_pkrtz(p0 * qsc, p1 * qsc);
            qp.h2[1] = __builtin_amdgcn_cvt_pkrtz(p2 * qsc, p3 * qsc);
            // q[k=lr][m=lhi*4..+3] into node (t,g2)'s [16k][16m] subtile
            *(uint2*)(qwb + t * 1024 + g2 * 256) = qp.u2;
        }
    }
    asm volatile("s_waitcnt lgkmcnt(0)" ::: "memory");  // q writes retired
    // ---- qf via hardware-transpose reads (one batch, 8 frags) ----
    const u32 qtr = (u32)(size_t)qlds + wave * 4096 + lane * 8;
    f16x4 qf[2][4];
    #pragma unroll
    for (int t = 0; t < 2; ++t)
        #pragma unroll
        for (int g2 = 0; g2 < 4; ++g2)
            qf[t][g2] = tr_read(qtr + t * 2048 + g2 * 512);
    asm volatile("s_waitcnt lgkmcnt(0)" ::: "memory");
    __builtin_amdgcn_sched_barrier(0);                  // rule #18

    // ---- Bcomp (transpose+contract pair, pkrtz pack) -> slds ----
    #pragma unroll
    for (int t = 0; t < 2; ++t)
        #pragma unroll
        for (int g2 = 0; g2 < 4; ++g2) {
            const int rnode = t * 16 + wave * 4 + g2;
            #pragma unroll
            for (int cc = 0; cc < 4; ++cc) {
                f32x4 xt = {0.f,0.f,0.f,0.f};
                xt = __builtin_amdgcn_mfma_f32_16x16x32_f16(
                         (cc < 2) ? gLo[t][g2] : gHi[t][g2], idf[cc & 1], xt, 0, 0, 0);
                union { fp16v2 h2[2]; f16x4 h4; } at;
                at.h2[0] = __builtin_amdgcn_cvt_pkrtz(xt[0], xt[1]);
                at.h2[1] = __builtin_amdgcn_cvt_pkrtz(xt[2], xt[3]);
                f32x4 d2 = {0.f,0.f,0.f,0.f};
                d2 = __builtin_amdgcn_mfma_f32_16x16x16f16(at.h4, qf[t][g2], d2, 0, 0, 0);
                union { fp16v2 h2[2]; uint2 u2; } sp;
                sp.h2[0] = __builtin_amdgcn_cvt_pkrtz(d2[0], d2[1]);
                sp.h2[1] = __builtin_amdgcn_cvt_pkrtz(d2[2], d2[3]);
                if (lr < 9) {
                    // kf = lr*64 + cc*16 + lhi*4 ; q = kf>>3 ; m = kf>>6 = lr
                    int q_ = lr * 8 + cc * 2 + (lhi >> 1);
                    int idx = (((q_ * 32 + rnode) << 3) ^ ((lr & 7) << 3)) + (lhi & 1) * 4;
                    *(uint2*)(slds + idx) = sp.u2;
                }
            }
        }
    __syncthreads();

    // ---- Phase C (merged, each bf load feeds both tiles) ----
    const int o0 = wave * 16;
    const float bv = bias[o0 + lr];
    f32x4 a0 = {0.f,0.f,0.f,0.f}, a1 = {0.f,0.f,0.f,0.f};
    #pragma unroll
    for (int ks = 0; ks < NKS; ++ks) {
        int q_ = ks * 4 + lhi;                     // m = q_>>3 (wave-uniform per ks)
        int sw = ((q_ >> 3) & 7) << 3;
        f16x8 af0 = *(const f16x8*)(slds + ((((q_ * 32) + lr) << 3) ^ sw));
        f16x8 af1 = *(const f16x8*)(slds + ((((q_ * 32) + 16 + lr) << 3) ^ sw));
        f16x8 bf  = *(const f16x8*)(wfb2 + (size_t)(q_ * 64 + o0 + lr) * 8);
        a0 = __builtin_amdgcn_mfma_f32_16x16x32_f16(af0, bf, a0, 0, 0, 0);
        a1 = __builtin_amdgcn_mfma_f32_16x16x32_f16(af1, bf, a1, 0, 0, 0);
    }
    #pragma unroll
    for (int r = 0; r < 4; ++r) {
        out[(size_t)(node0 + lhi * 4 + r) * OO + o0 + lr]      = a0[r] + bv;
        out[(size_t)(node0 + 16 + lhi * 4 + r) * OO + o0 + lr] = a1[r] + bv;
    }
}

// ---------------------------------------------------------------------------
extern "C" void kernel_launch(void* const* d_in, const int* in_sizes, int n_in,
                              void* d_out, int out_size, void* d_ws, size_t ws_size,
                              hipStream_t stream)
{
    const float* x   = (const float*)d_in[0];
    const int*   adj = (const int*)  d_in[1];
    const float* W   = (const float*)d_in[2];
    const float* b   = (const float*)d_in[3];
    const float* u   = (const float*)d_in[4];
    const float* v   = (const float*)d_in[5];
    const float* c   = (const float*)d_in[6];
    float* out = (float*)d_out;

    // workspace: uxc f32 [BN*16] | xh f16 [BN*64] | wfb2 [36864] | vfa [1024]
    float* uxc  = (float*)d_ws;
    u16*   xh   = (u16*)(uxc + (size_t)BN * UVP);
    u16*   wfb2 = xh + (size_t)BN * CC;
    u16*   vfa  = wfb2 + 36864;

    pre_kernel<<<1287, 256, 0, stream>>>(x, W, u, v, c, uxc, xh, wfb2, vfa);
    fused_kernel<<<2504, 256, 0, stream>>>(xh, adj, uxc, wfb2, vfa, b, out);
}